// Round 4
// baseline (195.646 us; speedup 1.0000x reference)
//
#include <hip/hip_runtime.h>

// TransientGenerator, scatter-into-LDS formulation.
// One block per (batch, 4096-sample segment). LDS holds the segment
// accumulator; transients scatter-add via ds_add_f32 (atomic, no-return,
// no barriers needed between transients). Sorted timings -> overlapping
// transient range is contiguous; found with one per-thread test +
// LDS atomicMin/Max. Every output element is written exactly once.

constexpr int SR   = 16000;  // SAMPLE_RATE
constexpr int TL   = 1600;   // TRANSIENT_SAMPLES
constexpr int MAXT = 256;    // MAX_TRANSIENTS
constexpr int SEG  = 4096;   // samples per block segment (16 KB LDS)
constexpr int NTHR = 256;

__global__ __launch_bounds__(NTHR)
void transient_seg(const float* __restrict__ timings,   // [B,T]
                   const int*   __restrict__ ids,       // [B,T]
                   const float* __restrict__ gains,     // [B,T]
                   const float* __restrict__ templates, // [n_tr,TL]
                   float*       __restrict__ out,       // [B,A]
                   int T, int n_tr, int A)
{
    __shared__ float s_acc[SEG];
    __shared__ int   s_lo, s_hi;

    const int b    = blockIdx.y;
    const int seg0 = blockIdx.x * SEG;
    const int tid  = (int)threadIdx.x;

    // Zero the accumulator (4 x float4 per thread).
    float4* a4 = reinterpret_cast<float4*>(s_acc);
#pragma unroll
    for (int k = 0; k < SEG / (4 * NTHR); ++k)
        a4[tid + k * NTHR] = make_float4(0.f, 0.f, 0.f, 0.f);

    if (tid == 0) { s_lo = T; s_hi = -1; }
    __syncthreads();

    // Overlap range: ts in (seg0 - TL, seg0 + SEG). Sorted ts => contiguous in j.
    for (int j = tid; j < T; j += NTHR) {
        const float tm = timings[(size_t)b * T + j];
        const int   ts = (int)floorf(tm * (float)SR);   // matches jnp.floor(t*SR) in fp32
        if (ts + TL > seg0 && ts < seg0 + SEG) {
            atomicMin(&s_lo, j);
            atomicMax(&s_hi, j);
        }
    }
    __syncthreads();

    const int lo = s_lo, hi = s_hi;

    for (int j = lo; j <= hi; ++j) {                    // uniform loop, ~10 iters
        const float tm = timings[(size_t)b * T + j];
        const float g  = gains  [(size_t)b * T + j];
        const int   id = ids    [(size_t)b * T + j];
        const int   ts = (int)floorf(tm * (float)SR);
        // reference valid mask: gain > 0, id < n_tr, ts < audio_length
        if (!((g > 0.0f) & (id < n_tr) & (ts < A))) continue;   // uniform branch
        const float* __restrict__ row = templates + (size_t)min(max(id, 0), n_tr - 1) * TL;
        const int base = ts - seg0;                      // in (-TL, SEG)
        for (int t = tid; t < TL; t += NTHR) {           // coalesced template sweep
            const int p = base + t;
            if ((unsigned)p < (unsigned)SEG)
                atomicAdd(&s_acc[p], g * row[t]);        // ds_add_f32, fire-and-forget
        }
    }
    __syncthreads();

    // Write the segment out — every covered output element exactly once.
    const int remain = A - seg0;                         // < SEG only on last segment
    float* ob = out + (size_t)b * A + seg0;
    if ((((size_t)ob) & 15) == 0) {
#pragma unroll
        for (int k = 0; k < SEG / (4 * NTHR); ++k) {
            const int i4 = tid + k * NTHR;
            const int p  = i4 * 4;
            if (p + 3 < remain) {
                reinterpret_cast<float4*>(ob)[i4] =
                    make_float4(s_acc[p], s_acc[p + 1], s_acc[p + 2], s_acc[p + 3]);
            } else if (p < remain) {
                for (int e = 0; e < 4 && p + e < remain; ++e) ob[p + e] = s_acc[p + e];
            }
        }
    } else {
        for (int p = tid; p < SEG && p < remain; p += NTHR) ob[p] = s_acc[p];
    }
}

extern "C" void kernel_launch(void* const* d_in, const int* in_sizes, int n_in,
                              void* d_out, int out_size, void* d_ws, size_t ws_size,
                              hipStream_t stream) {
    const float* timings   = (const float*)d_in[0];
    const int*   ids       = (const int*)  d_in[1];
    const float* gains     = (const float*)d_in[2];
    const float* templates = (const float*)d_in[3];
    float*       out       = (float*)d_out;

    const int T    = MAXT;                 // reference MAX_TRANSIENTS
    const int B    = in_sizes[0] / T;
    const int n_tr = in_sizes[3] / TL;     // templates are [n_tr, TL]
    const int A    = out_size / B;         // audio_length

    dim3 grid((A + SEG - 1) / SEG, B), block(NTHR);
    transient_seg<<<grid, block, 0, stream>>>(timings, ids, gains, templates, out,
                                              T, n_tr, A);
}

// Round 5
// 26.203 us; speedup vs baseline: 7.4666x; 7.4666x over previous
//
#include <hip/hip_runtime.h>

// TransientGenerator, gather with stride-64 lane mapping.
// One block per (batch, 1024-sample chunk); thread tid owns samples
// chunk0 + tid + k*256 (k=0..3) so template loads are lane-consecutive
// (4 L1 lines per wave-load instead of 16 with the old 16B lane stride).
// Overlap range [lo,hi] found via one ballot (sorted ts => interval),
// replacing the 8-step serially-dependent LDS binary search.

constexpr int SR    = 16000;  // SAMPLE_RATE
constexpr int TL    = 1600;   // TRANSIENT_SAMPLES
constexpr int MAXT  = 256;    // MAX_TRANSIENTS (== blockDim)
constexpr int NTHR  = 256;
constexpr int CHUNK = 1024;   // NTHR * 4 samples per block

__global__ __launch_bounds__(NTHR)
void transient_gather(const float* __restrict__ timings,   // [B,T]
                      const int*   __restrict__ ids,       // [B,T]
                      const float* __restrict__ gains,     // [B,T]
                      const float* __restrict__ templates, // [n_tr,TL]
                      float*       __restrict__ out,       // [B,A]
                      int T, int n_tr, int A)
{
    __shared__ int2               s_m[MAXT];   // .x = (ts<<8)|id (clamped), .y = gain bits (0 if invalid)
    __shared__ unsigned long long s_mask[NTHR / 64];

    const int b      = blockIdx.y;
    const int chunk0 = blockIdx.x * CHUNK;
    const int tid    = (int)threadIdx.x;

    // Stage transient j = tid (T == NTHR) and test window overlap.
    {
        const float tm = timings[(size_t)b * T + tid];
        const float g  = gains  [(size_t)b * T + tid];
        const int   id = ids    [(size_t)b * T + tid];
        const int   ts = (int)floorf(tm * (float)SR);   // matches jnp.floor(t*SR) in fp32
        const bool ok  = (g > 0.0f) & (id < n_tr) & (ts < A);
        const int tsc  = min(max(ts, 0), A);            // clamp preserves sorted order
        const int idc  = min(max(id, 0), n_tr - 1);
        s_m[tid] = make_int2((tsc << 8) | idc, ok ? __float_as_int(g) : 0);

        // overlap iff ts < chunk_end && ts + TL > chunk0  (interval in sorted ts)
        const bool ov = (tsc < chunk0 + CHUNK) && (tsc + TL > chunk0);
        const unsigned long long m = __ballot(ov);
        if ((tid & 63) == 0) s_mask[tid >> 6] = m;
    }
    __syncthreads();

    int lo = T, hi = -1;
#pragma unroll
    for (int w = 0; w < NTHR / 64; ++w) {
        const unsigned long long mw = s_mask[w];
        if (mw) {
            lo = min(lo, w * 64 + (int)__builtin_ctzll(mw));
            hi = max(hi, w * 64 + 63 - (int)__builtin_clzll(mw));
        }
    }

    float acc[4] = {0.f, 0.f, 0.f, 0.f};
    const int off_base = chunk0 + tid;                  // sample index of k=0

    for (int j = lo; j <= hi; ++j) {                    // known trip count, no break
        const int2  m  = s_m[j];                        // uniform -> broadcast ds_read_b64
        const int   ts = m.x >> 8;
        const float g  = __int_as_float(m.y);
        const float* __restrict__ row = templates + (size_t)(m.x & 255) * TL;
        const int off0 = off_base - ts;
#pragma unroll
        for (int k = 0; k < 4; ++k) {
            const int o = off0 + k * NTHR;
            if ((unsigned)o < (unsigned)TL)             // exec-masked, lane-consecutive load
                acc[k] += g * row[o];
        }
    }

    float* ob = out + (size_t)b * A + off_base;
#pragma unroll
    for (int k = 0; k < 4; ++k) {
        if (off_base + k * NTHR < A) ob[k * NTHR] = acc[k];   // coalesced dword store
    }
}

extern "C" void kernel_launch(void* const* d_in, const int* in_sizes, int n_in,
                              void* d_out, int out_size, void* d_ws, size_t ws_size,
                              hipStream_t stream) {
    const float* timings   = (const float*)d_in[0];
    const int*   ids       = (const int*)  d_in[1];
    const float* gains     = (const float*)d_in[2];
    const float* templates = (const float*)d_in[3];
    float*       out       = (float*)d_out;

    const int T    = MAXT;                 // reference MAX_TRANSIENTS
    const int B    = in_sizes[0] / T;
    const int n_tr = in_sizes[3] / TL;     // templates are [n_tr, TL]
    const int A    = out_size / B;         // audio_length

    dim3 grid((A + CHUNK - 1) / CHUNK, B), block(NTHR);
    transient_gather<<<grid, block, 0, stream>>>(timings, ids, gains, templates, out,
                                                 T, n_tr, A);
}